// Round 14
// baseline (484.265 us; speedup 1.0000x reference)
//
#include <hip/hip_runtime.h>
#include <hip/hip_bf16.h>
#include <math.h>

#define PI_F 3.14159265358979323846f
#define BK_SHIFT 8            // bucket = dst >> 8 (256 nodes per bucket)
#define P2_CHUNK 4096
#define P2_PER_THREAD 16

typedef __attribute__((ext_vector_type(8))) short bf16x8;
typedef __attribute__((ext_vector_type(4))) float f32x4;
typedef __attribute__((ext_vector_type(4))) unsigned short u16x4;
typedef __attribute__((ext_vector_type(8))) unsigned short u16x8;

__device__ __forceinline__ float bf2f(unsigned short u) {
    union { unsigned int i; float f; } v;
    v.i = ((unsigned int)u) << 16;
    return v.f;
}

__device__ __forceinline__ unsigned short f2bf_bits(float f) {
    __hip_bfloat16 b = __float2bfloat16(f);
    unsigned short u;
    __builtin_memcpy(&u, &b, 2);
    return u;
}

// ---------------- binning (counting sort by dst) ----------------

__global__ void count_kernel(const int* __restrict__ dst, int* __restrict__ cnt, int E) {
    int e = blockIdx.x * 256 + threadIdx.x;
    if (e < E) atomicAdd(&cnt[dst[e]], 1);
}

__global__ __launch_bounds__(256) void scan_reduce_kernel(const int* __restrict__ cnt,
                                                          int* __restrict__ bsum, int n) {
    __shared__ int sd[4];
    int idx = blockIdx.x * 256 + threadIdx.x;
    int v = (idx < n) ? cnt[idx] : 0;
    int s = v;
#pragma unroll
    for (int m = 1; m < 64; m <<= 1) s += __shfl_xor(s, m, 64);
    int wave = threadIdx.x >> 6;
    if ((threadIdx.x & 63) == 0) sd[wave] = s;
    __syncthreads();
    if (threadIdx.x == 0) bsum[blockIdx.x] = sd[0] + sd[1] + sd[2] + sd[3];
}

__global__ __launch_bounds__(256) void scan_top_kernel(const int* __restrict__ bsum,
                                                       int* __restrict__ boffs, int nb) {
    __shared__ int sd[256];
    int tid = threadIdx.x;
    int v = (tid < nb) ? bsum[tid] : 0;
    sd[tid] = v;
    __syncthreads();
#pragma unroll
    for (int off = 1; off < 256; off <<= 1) {
        int t = (tid >= off) ? sd[tid - off] : 0;
        __syncthreads();
        sd[tid] += t;
        __syncthreads();
    }
    if (tid < nb) boffs[tid] = sd[tid] - v;  // exclusive
}

__global__ __launch_bounds__(256) void scan_apply_kernel(int* __restrict__ cntcur,
                                                         int* __restrict__ offs,
                                                         const int* __restrict__ boffs,
                                                         int n, int total) {
    __shared__ int sd[256];
    int tid = threadIdx.x;
    int idx = blockIdx.x * 256 + tid;
    int v = (idx < n) ? cntcur[idx] : 0;
    sd[tid] = v;
    __syncthreads();
#pragma unroll
    for (int off = 1; off < 256; off <<= 1) {
        int t = (tid >= off) ? sd[tid - off] : 0;
        __syncthreads();
        sd[tid] += t;
        __syncthreads();
    }
    if (idx < n) offs[idx] = boffs[blockIdx.x] + sd[tid] - v;
    if (idx == 0) offs[n] = total;
}

// bucketCursor[b] = offs[b<<8]
__global__ void bucket_init_kernel(const int* __restrict__ offs, int* __restrict__ bucketCursor,
                                   int nbuk, int nN) {
    int b = blockIdx.x * 256 + threadIdx.x;
    if (b < nbuk) bucketCursor[b] = offs[min(b << BK_SHIFT, nN)];
}

// pass 2: LDS counting-sort each 4096-edge chunk by bucket; bucket runs written contiguously.
__global__ __launch_bounds__(256) void bucket_scatter_kernel(const int* __restrict__ dst,
                                                             int* __restrict__ bucketCursor,
                                                             int* __restrict__ inter,
                                                             int E, int nbuk) {
    __shared__ int lcnt[256];
    __shared__ int lbase[256];
    __shared__ int lgpos[256];
    __shared__ int lsort[P2_CHUNK];
    __shared__ unsigned char lbuk[P2_CHUNK];
    int tid = threadIdx.x;
    int base = blockIdx.x * P2_CHUNK;
    lcnt[tid] = 0;
    __syncthreads();
    int myb[P2_PER_THREAD], myr[P2_PER_THREAD];
#pragma unroll
    for (int i = 0; i < P2_PER_THREAD; i++) {
        int idx = base + i * 256 + tid;
        int b = -1, r = 0;
        if (idx < E) {
            b = dst[idx] >> BK_SHIFT;
            r = atomicAdd(&lcnt[b], 1);
        }
        myb[i] = b;
        myr[i] = r;
    }
    __syncthreads();
    int v = lcnt[tid];
    lbase[tid] = v;
    __syncthreads();
    for (int off = 1; off < 256; off <<= 1) {
        int t = (tid >= off) ? lbase[tid - off] : 0;
        __syncthreads();
        lbase[tid] += t;
        __syncthreads();
    }
    int excl = lbase[tid] - v;
    if (tid < nbuk && v > 0) lgpos[tid] = atomicAdd(&bucketCursor[tid], v);
    __syncthreads();
    lbase[tid] = excl;
    __syncthreads();
#pragma unroll
    for (int i = 0; i < P2_PER_THREAD; i++) {
        if (myb[i] >= 0) {
            int p = lbase[myb[i]] + myr[i];
            lsort[p] = base + i * 256 + tid;
            lbuk[p] = (unsigned char)myb[i];
        }
    }
    __syncthreads();
    int total = (base + P2_CHUNK <= E) ? P2_CHUNK : (E > base ? E - base : 0);
    for (int idx = tid; idx < total; idx += 256) {
        int b = lbuk[idx];
        inter[lgpos[b] + (idx - lbase[b])] = lsort[idx];
    }
}

// pass 3: one block per bucket; finish sort with LDS cursors; single-writer output region.
__global__ __launch_bounds__(256) void bucket_sort_fill_kernel(const int* __restrict__ inter,
                                                               const int* __restrict__ dst,
                                                               const int* __restrict__ src,
                                                               const float* __restrict__ el,
                                                               const int* __restrict__ offs,
                                                               int* __restrict__ srcS,
                                                               unsigned short* __restrict__ basisB,
                                                               int nN) {
    __shared__ int cursor[256];
    int b = blockIdx.x;
    int n0 = b << BK_SHIFT;
    int n1 = min(n0 + 256, nN);
    int tid = threadIdx.x;
    int p0 = offs[n0];
    int p1 = offs[n1];
    if (tid < n1 - n0) cursor[tid] = offs[n0 + tid];
    __syncthreads();
    for (int q = p0 + tid; q < p1; q += 256) {
        int e = inter[q];
        int d = dst[e];
        int pos = atomicAdd(&cursor[d - n0], 1);
        srcS[pos] = src[e];
        float2 xy = *(const float2*)(el + 2 * (size_t)e);
        u16x8 p;
        p[0] = f2bf_bits(1.0f);
        p[1] = f2bf_bits(__sinf(PI_F * xy.x));
        p[2] = f2bf_bits(__cosf(PI_F * xy.x));
        p[3] = f2bf_bits(__sinf(2.0f * PI_F * xy.x));
        p[4] = f2bf_bits(1.0f);
        p[5] = f2bf_bits(__sinf(PI_F * xy.y));
        p[6] = f2bf_bits(__cosf(PI_F * xy.y));
        p[7] = f2bf_bits(__sinf(2.0f * PI_F * xy.y));
        *(u16x8*)(basisB + (size_t)pos * 8) = p;
    }
}

// ---------------- preps ----------------

__global__ void prep_w_kernel(const float* __restrict__ W, __hip_bfloat16* __restrict__ Wt, int K) {
    int i = blockIdx.x * 256 + threadIdx.x;
    if (i >= K * 64) return;
    int k = i >> 6, o = i & 63;
    Wt[(size_t)o * K + k] = __float2bfloat16(W[i]);
}

__global__ void prep_f2b_kernel(const float* __restrict__ in, __hip_bfloat16* __restrict__ out, int n) {
    int i = blockIdx.x * 256 + threadIdx.x;
    if (i < n) out[i] = __float2bfloat16(in[i]);
}

// ---------------- agg F=64: wave per node, lane = (eg 0..3, fg 0..15) ----------------
// depth-1 3-stage loop-carried pipeline (r11 best). BLOCK = 1024 (16 waves):
// same waves/work, 4x fewer workgroups -> tests/raises the dispatch-rate ceiling.

__device__ __forceinline__ void agg64_core(const unsigned short* __restrict__ hp,
                                           const int* __restrict__ srcS,
                                           const unsigned short* __restrict__ basisB,
                                           int start, int end, int eg, int fb,
                                           float acc[8][4]) {
    const int last = end - 1;
    int j = start;
    int qa = min(j + eg, last), qb = min(j + 4 + eg, last);
    int sa = srcS[qa], sb = srcS[qb];
    u16x4 ga = *(const u16x4*)(hp + (size_t)sa * 64 + fb);
    u16x4 gb = *(const u16x4*)(hp + (size_t)sb * 64 + fb);
    u16x8 ca = *(const u16x8*)(basisB + (size_t)qa * 8);
    u16x8 cb = *(const u16x8*)(basisB + (size_t)qb * 8);
    int qna = min(j + 8 + eg, last), qnb = min(j + 12 + eg, last);
    int sna = srcS[qna], snb = srcS[qnb];
    while (true) {
        int jn = j + 8;
        int q2a = min(jn + 8 + eg, last), q2b = min(jn + 12 + eg, last);
        int s2a = srcS[q2a], s2b = srcS[q2b];
        u16x4 gna = *(const u16x4*)(hp + (size_t)sna * 64 + fb);
        u16x4 gnb = *(const u16x4*)(hp + (size_t)snb * 64 + fb);
        u16x8 cna = *(const u16x8*)(basisB + (size_t)qna * 8);
        u16x8 cnb = *(const u16x8*)(basisB + (size_t)qnb * 8);
        float ha[4], hb[4];
        ha[0] = bf2f(ga[0]); ha[1] = bf2f(ga[1]); ha[2] = bf2f(ga[2]); ha[3] = bf2f(ga[3]);
        hb[0] = bf2f(gb[0]); hb[1] = bf2f(gb[1]); hb[2] = bf2f(gb[2]); hb[3] = bf2f(gb[3]);
        if (j + eg >= end)     { ha[0] = 0.f; ha[1] = 0.f; ha[2] = 0.f; ha[3] = 0.f; }
        if (j + 4 + eg >= end) { hb[0] = 0.f; hb[1] = 0.f; hb[2] = 0.f; hb[3] = 0.f; }
#pragma unroll
        for (int b = 0; b < 8; b++) {
            float w = bf2f(ca[b]);
#pragma unroll
            for (int c = 0; c < 4; c++) acc[b][c] += w * ha[c];
        }
#pragma unroll
        for (int b = 0; b < 8; b++) {
            float w = bf2f(cb[b]);
#pragma unroll
            for (int c = 0; c < 4; c++) acc[b][c] += w * hb[c];
        }
        if (jn >= end) break;
        j = jn;
        ga = gna; gb = gnb; ca = cna; cb = cnb;
        qna = q2a; qnb = q2b; sna = s2a; snb = s2b;
    }
}

__global__ __launch_bounds__(1024) void agg64_kernel(const __hip_bfloat16* __restrict__ h,
                                                     const int* __restrict__ srcS,
                                                     const unsigned short* __restrict__ basisB,
                                                     const int* __restrict__ offs,
                                                     __hip_bfloat16* __restrict__ A, int nN) {
    int wid = (blockIdx.x * 1024 + threadIdx.x) >> 6;
    int lane = threadIdx.x & 63;
    if (wid >= nN) return;
    int eg = lane >> 4, fg = lane & 15;
    int start = offs[wid], end = offs[wid + 1];
    float acc[8][4] = {};
    if (start < end)
        agg64_core((const unsigned short*)h, srcS, basisB, start, end, eg, fg * 4, acc);
#pragma unroll
    for (int b = 0; b < 8; b++) {
#pragma unroll
        for (int c = 0; c < 4; c++) {
            float v = acc[b][c];
            v += __shfl_xor(v, 16, 64);
            v += __shfl_xor(v, 32, 64);
            acc[b][c] = v;
        }
    }
    if (eg == 0) {
        unsigned short* Ar = (unsigned short*)A + (size_t)wid * 512;
#pragma unroll
        for (int b = 0; b < 8; b++) {
            u16x4 p;
            p[0] = f2bf_bits(acc[b][0]); p[1] = f2bf_bits(acc[b][1]);
            p[2] = f2bf_bits(acc[b][2]); p[3] = f2bf_bits(acc[b][3]);
            *(u16x4*)(Ar + b * 64 + fg * 4) = p;
        }
    }
}

// fused final layer: agg64 + [512x2] contraction + scale
__global__ __launch_bounds__(1024) void agg_out_kernel(const __hip_bfloat16* __restrict__ h,
                                                       const int* __restrict__ srcS,
                                                       const unsigned short* __restrict__ basisB,
                                                       const int* __restrict__ offs,
                                                       const float* __restrict__ W3,
                                                       float* __restrict__ out, int nN) {
    int wid = (blockIdx.x * 1024 + threadIdx.x) >> 6;
    int lane = threadIdx.x & 63;
    if (wid >= nN) return;
    int eg = lane >> 4, fg = lane & 15;
    int start = offs[wid], end = offs[wid + 1];
    float acc[8][4] = {};
    if (start < end)
        agg64_core((const unsigned short*)h, srcS, basisB, start, end, eg, fg * 4, acc);
#pragma unroll
    for (int b = 0; b < 8; b++) {
#pragma unroll
        for (int c = 0; c < 4; c++) {
            float v = acc[b][c];
            v += __shfl_xor(v, 16, 64);
            v += __shfl_xor(v, 32, 64);
            acc[b][c] = v;
        }
    }
    float o0 = 0.f, o1 = 0.f;
#pragma unroll
    for (int b = 0; b < 8; b++) {
        const float* w = W3 + (size_t)(b * 64 + fg * 4) * 2;
        float4 wa = *(const float4*)w;
        float4 wb = *(const float4*)(w + 4);
        o0 += acc[b][0] * wa.x + acc[b][1] * wa.z + acc[b][2] * wb.x + acc[b][3] * wb.z;
        o1 += acc[b][0] * wa.y + acc[b][1] * wa.w + acc[b][2] * wb.y + acc[b][3] * wb.w;
    }
#pragma unroll
    for (int m = 1; m < 16; m <<= 1) {
        o0 += __shfl_xor(o0, m, 64);
        o1 += __shfl_xor(o1, m, 64);
    }
    if (lane == 0) {
        out[(size_t)wid * 2 + 0] = o0 * (1.0f / 128.0f);
        out[(size_t)wid * 2 + 1] = o1 * (1.0f / 128.0f);
    }
}

// ---------------- agg F=16: wave per node, lane = (eg 0..15, fg 0..3) ----------------

__global__ __launch_bounds__(1024) void agg16_kernel(const __hip_bfloat16* __restrict__ h,
                                                     const int* __restrict__ srcS,
                                                     const unsigned short* __restrict__ basisB,
                                                     const int* __restrict__ offs,
                                                     __hip_bfloat16* __restrict__ A, int nN) {
    int wid = (blockIdx.x * 1024 + threadIdx.x) >> 6;
    int lane = threadIdx.x & 63;
    if (wid >= nN) return;
    int eg = lane >> 2, fg = lane & 3;
    int start = offs[wid], end = offs[wid + 1];
    float acc[8][4] = {};
    if (start < end) {
        const unsigned short* hp = (const unsigned short*)h;
        const int last = end - 1;
        const int fb = fg * 4;
        int j = start;
        int q = min(j + eg, last);
        int s = srcS[q];
        u16x4 g = *(const u16x4*)(hp + (size_t)s * 16 + fb);
        u16x8 cbv = *(const u16x8*)(basisB + (size_t)q * 8);
        int qn = min(j + 16 + eg, last);
        int sn = srcS[qn];
        while (true) {
            int jn = j + 16;
            int q2 = min(jn + 16 + eg, last);
            int s2 = srcS[q2];
            u16x4 gn = *(const u16x4*)(hp + (size_t)sn * 16 + fb);
            u16x8 cn = *(const u16x8*)(basisB + (size_t)qn * 8);
            float hv[4];
            hv[0] = bf2f(g[0]); hv[1] = bf2f(g[1]); hv[2] = bf2f(g[2]); hv[3] = bf2f(g[3]);
            if (j + eg >= end) { hv[0] = 0.f; hv[1] = 0.f; hv[2] = 0.f; hv[3] = 0.f; }
#pragma unroll
            for (int b = 0; b < 8; b++) {
                float w = bf2f(cbv[b]);
#pragma unroll
                for (int c = 0; c < 4; c++) acc[b][c] += w * hv[c];
            }
            if (jn >= end) break;
            j = jn;
            g = gn; cbv = cn; qn = q2; sn = s2;
        }
    }
#pragma unroll
    for (int b = 0; b < 8; b++) {
#pragma unroll
        for (int c = 0; c < 4; c++) {
            float v = acc[b][c];
            v += __shfl_xor(v, 4, 64);
            v += __shfl_xor(v, 8, 64);
            v += __shfl_xor(v, 16, 64);
            v += __shfl_xor(v, 32, 64);
            acc[b][c] = v;
        }
    }
    if (eg == 0) {
        unsigned short* Ar = (unsigned short*)A + (size_t)wid * 128;
#pragma unroll
        for (int b = 0; b < 8; b++) {
            u16x4 p;
            p[0] = f2bf_bits(acc[b][0]); p[1] = f2bf_bits(acc[b][1]);
            p[2] = f2bf_bits(acc[b][2]); p[3] = f2bf_bits(acc[b][3]);
            *(u16x4*)(Ar + b * 16 + fg * 4) = p;
        }
    }
}

// ---------------- MFMA GEMM: Hout[n, 0..63] = relu(A[n, :K] @ Wt^T), bf16 out ----------------
// Frags (16x16x32 bf16): A/B lane mapping m/n = lane&15, k = (lane>>4)*8 + j.
// C/D: col = lane&15, row = (lane>>4)*4 + reg  [verified m89].

template <int K, bool RELU>
__global__ __launch_bounds__(256) void gemm_mfma_kernel(const __hip_bfloat16* __restrict__ A,
                                                        const __hip_bfloat16* __restrict__ Wt,
                                                        __hip_bfloat16* __restrict__ Hout, int nN) {
    int wave = threadIdx.x >> 6;
    int lane = threadIdx.x & 63;
    int m16 = lane & 15;
    int kg = lane >> 4;  // 0..3
    int arow = blockIdx.x * 64 + wave * 16 + m16;
    bool rowok = arow < nN;
    const short* Ap = (const short*)A;
    const short* Wp = (const short*)Wt;
    size_t abase = (size_t)arow * K + kg * 8;
    size_t wb0 = (size_t)(0 * 16 + m16) * K + kg * 8;
    size_t wb1 = (size_t)(1 * 16 + m16) * K + kg * 8;
    size_t wb2 = (size_t)(2 * 16 + m16) * K + kg * 8;
    size_t wb3 = (size_t)(3 * 16 + m16) * K + kg * 8;
    f32x4 acc0 = {0.f, 0.f, 0.f, 0.f};
    f32x4 acc1 = {0.f, 0.f, 0.f, 0.f};
    f32x4 acc2 = {0.f, 0.f, 0.f, 0.f};
    f32x4 acc3 = {0.f, 0.f, 0.f, 0.f};
#pragma unroll 4
    for (int kc = 0; kc < K; kc += 32) {
        bf16x8 af = {};
        if (rowok) af = *(const bf16x8*)(Ap + abase + kc);
        bf16x8 b0 = *(const bf16x8*)(Wp + wb0 + kc);
        bf16x8 b1 = *(const bf16x8*)(Wp + wb1 + kc);
        bf16x8 b2 = *(const bf16x8*)(Wp + wb2 + kc);
        bf16x8 b3 = *(const bf16x8*)(Wp + wb3 + kc);
        acc0 = __builtin_amdgcn_mfma_f32_16x16x32_bf16(af, b0, acc0, 0, 0, 0);
        acc1 = __builtin_amdgcn_mfma_f32_16x16x32_bf16(af, b1, acc1, 0, 0, 0);
        acc2 = __builtin_amdgcn_mfma_f32_16x16x32_bf16(af, b2, acc2, 0, 0, 0);
        acc3 = __builtin_amdgcn_mfma_f32_16x16x32_bf16(af, b3, acc3, 0, 0, 0);
    }
    int orow0 = blockIdx.x * 64 + wave * 16 + kg * 4;
#pragma unroll
    for (int r = 0; r < 4; r++) {
        int row = orow0 + r;
        if (row < nN) {
            float v0 = acc0[r], v1 = acc1[r], v2 = acc2[r], v3 = acc3[r];
            if (RELU) {
                v0 = fmaxf(v0, 0.0f); v1 = fmaxf(v1, 0.0f);
                v2 = fmaxf(v2, 0.0f); v3 = fmaxf(v3, 0.0f);
            }
            __hip_bfloat16* Hr = Hout + (size_t)row * 64;
            Hr[0 * 16 + m16] = __float2bfloat16(v0);
            Hr[1 * 16 + m16] = __float2bfloat16(v1);
            Hr[2 * 16 + m16] = __float2bfloat16(v2);
            Hr[3 * 16 + m16] = __float2bfloat16(v3);
        }
    }
}

// ---------------- launch ----------------

extern "C" void kernel_launch(void* const* d_in, const int* in_sizes, int n_in,
                              void* d_out, int out_size, void* d_ws, size_t ws_size,
                              hipStream_t stream) {
    const float* x  = (const float*)d_in[0];
    const int*   ei = (const int*)d_in[1];
    const float* el = (const float*)d_in[2];
    const float* W0 = (const float*)d_in[3];
    const float* W1 = (const float*)d_in[4];
    const float* W2 = (const float*)d_in[5];
    const float* W3 = (const float*)d_in[6];
    int nN = in_sizes[0] / 16;
    int E  = in_sizes[1] / 2;
    const int* src = ei;
    const int* dst = ei + E;

    char* ws = (char*)d_ws;
    size_t off = 0;
    auto alloc = [&](size_t bytes) -> void* {
        void* p = ws + off;
        off = (off + bytes + 255) & ~(size_t)255;
        return p;
    };
    int nsb  = (nN + 255) / 256;        // scan blocks (must be <= 256)
    int nbuk = (nN + 255) >> BK_SHIFT;  // buckets of 256 nodes
    int*   cntcur = (int*)alloc((size_t)(nN + 1) * 4);
    int*   offs   = (int*)alloc((size_t)(nN + 1) * 4);
    int*   bsum   = (int*)alloc((size_t)nsb * 4);
    int*   boffs  = (int*)alloc((size_t)nsb * 4);
    int*   bukcur = (int*)alloc((size_t)nbuk * 4);
    int*   inter  = (int*)alloc((size_t)E * 4);
    int*   srcS   = (int*)alloc((size_t)E * 4);
    unsigned short* basisB = (unsigned short*)alloc((size_t)E * 8 * 2);
    __hip_bfloat16* Ab  = (__hip_bfloat16*)alloc((size_t)nN * 512 * 2);
    __hip_bfloat16* Wt0 = (__hip_bfloat16*)alloc((size_t)64 * 128 * 2);
    __hip_bfloat16* Wt1 = (__hip_bfloat16*)alloc((size_t)64 * 512 * 2);
    __hip_bfloat16* Wt2 = (__hip_bfloat16*)alloc((size_t)64 * 512 * 2);
    __hip_bfloat16* xb  = (__hip_bfloat16*)alloc((size_t)nN * 16 * 2);
    __hip_bfloat16* hA  = (__hip_bfloat16*)alloc((size_t)nN * 64 * 2);
    __hip_bfloat16* hB  = (__hip_bfloat16*)alloc((size_t)nN * 64 * 2);
    (void)ws_size;

    hipMemsetAsync(cntcur, 0, (size_t)nN * 4, stream);
    int eb = (E + 255) / 256;
    count_kernel<<<eb, 256, 0, stream>>>(dst, cntcur, E);
    scan_reduce_kernel<<<nsb, 256, 0, stream>>>(cntcur, bsum, nN);
    scan_top_kernel<<<1, 256, 0, stream>>>(bsum, boffs, nsb);
    scan_apply_kernel<<<nsb, 256, 0, stream>>>(cntcur, offs, boffs, nN, E);
    bucket_init_kernel<<<(nbuk + 255) / 256, 256, 0, stream>>>(offs, bukcur, nbuk, nN);
    int p2b = (E + P2_CHUNK - 1) / P2_CHUNK;
    bucket_scatter_kernel<<<p2b, 256, 0, stream>>>(dst, bukcur, inter, E, nbuk);
    bucket_sort_fill_kernel<<<nbuk, 256, 0, stream>>>(inter, dst, src, el, offs, srcS, basisB, nN);

    // preps (independent of binning; tiny)
    prep_w_kernel<<<(128 * 64 + 255) / 256, 256, 0, stream>>>(W0, Wt0, 128);
    prep_w_kernel<<<(512 * 64 + 255) / 256, 256, 0, stream>>>(W1, Wt1, 512);
    prep_w_kernel<<<(512 * 64 + 255) / 256, 256, 0, stream>>>(W2, Wt2, 512);
    prep_f2b_kernel<<<(nN * 16 + 255) / 256, 256, 0, stream>>>(x, xb, nN * 16);

    int nb = (nN + 15) / 16;  // 1024-thread blocks, 16 waves = 16 nodes each
    int gb = (nN + 63) / 64;  // gemm tiles

    // layer 0: in=16 -> 64
    agg16_kernel<<<nb, 1024, 0, stream>>>(xb, srcS, basisB, offs, Ab, nN);
    gemm_mfma_kernel<128, true><<<gb, 256, 0, stream>>>(Ab, Wt0, hA, nN);
    // layer 1: 64 -> 64
    agg64_kernel<<<nb, 1024, 0, stream>>>(hA, srcS, basisB, offs, Ab, nN);
    gemm_mfma_kernel<512, true><<<gb, 256, 0, stream>>>(Ab, Wt1, hB, nN);
    // layer 2: 64 -> 64
    agg64_kernel<<<nb, 1024, 0, stream>>>(hB, srcS, basisB, offs, Ab, nN);
    gemm_mfma_kernel<512, true><<<gb, 256, 0, stream>>>(Ab, Wt2, hA, nN);
    // layer 3 fused: agg + [512x2] + scale
    agg_out_kernel<<<nb, 1024, 0, stream>>>(hA, srcS, basisB, offs, W3, (float*)d_out, nN);
}

// Round 15
// 382.946 us; speedup vs baseline: 1.2646x; 1.2646x over previous
//
#include <hip/hip_runtime.h>
#include <hip/hip_bf16.h>
#include <math.h>

#define PI_F 3.14159265358979323846f
#define BK_SHIFT 8            // bucket = dst >> 8 (256 nodes per bucket)
#define P2_CHUNK 4096
#define P2_PER_THREAD 16
#define BCAP 6144             // max edges per bucket (mean 5102, sd ~71 -> 14+ sd headroom)

typedef __attribute__((ext_vector_type(8))) short bf16x8;
typedef __attribute__((ext_vector_type(4))) float f32x4;
typedef __attribute__((ext_vector_type(4))) unsigned short u16x4;
typedef __attribute__((ext_vector_type(8))) unsigned short u16x8;

__device__ __forceinline__ float bf2f(unsigned short u) {
    union { unsigned int i; float f; } v;
    v.i = ((unsigned int)u) << 16;
    return v.f;
}

__device__ __forceinline__ unsigned short f2bf_bits(float f) {
    __hip_bfloat16 b = __float2bfloat16(f);
    unsigned short u;
    __builtin_memcpy(&u, &b, 2);
    return u;
}

// ---------------- binning: bucket-level count + scan ----------------

// LDS-aggregated bucket histogram: ~50K global atomics total (vs 1M node-level).
__global__ __launch_bounds__(256) void bucket_count_kernel(const int* __restrict__ dst,
                                                           int* __restrict__ bcnt, int E, int nbuk) {
    __shared__ int h[256];
    int tid = threadIdx.x;
    h[tid] = 0;
    __syncthreads();
    int base = blockIdx.x * P2_CHUNK;
    for (int i = tid; i < P2_CHUNK; i += 256) {
        int idx = base + i;
        if (idx < E) atomicAdd(&h[dst[idx] >> BK_SHIFT], 1);
    }
    __syncthreads();
    if (tid < nbuk && h[tid] > 0) atomicAdd(&bcnt[tid], h[tid]);
}

// one block: exclusive scan of bcnt[0..nbuk) -> bukbase (and cursor copy)
__global__ __launch_bounds__(256) void bucket_scan_kernel(const int* __restrict__ bcnt,
                                                          int* __restrict__ bukbase,
                                                          int* __restrict__ bukcur,
                                                          int nbuk, int E) {
    __shared__ int sd[256];
    int tid = threadIdx.x;
    int v = (tid < nbuk) ? bcnt[tid] : 0;
    sd[tid] = v;
    __syncthreads();
#pragma unroll
    for (int off = 1; off < 256; off <<= 1) {
        int t = (tid >= off) ? sd[tid - off] : 0;
        __syncthreads();
        sd[tid] += t;
        __syncthreads();
    }
    if (tid < nbuk) {
        int ex = sd[tid] - v;
        bukbase[tid] = ex;
        bukcur[tid] = ex;
    }
    if (tid == 0) bukbase[nbuk] = E;
}

// pass 2: LDS counting-sort each 4096-edge chunk by bucket; bucket runs written contiguously.
__global__ __launch_bounds__(256) void bucket_scatter_kernel(const int* __restrict__ dst,
                                                             int* __restrict__ bucketCursor,
                                                             int* __restrict__ inter,
                                                             int E, int nbuk) {
    __shared__ int lcnt[256];
    __shared__ int lbase[256];
    __shared__ int lgpos[256];
    __shared__ int lsort[P2_CHUNK];
    __shared__ unsigned char lbuk[P2_CHUNK];
    int tid = threadIdx.x;
    int base = blockIdx.x * P2_CHUNK;
    lcnt[tid] = 0;
    __syncthreads();
    int myb[P2_PER_THREAD], myr[P2_PER_THREAD];
#pragma unroll
    for (int i = 0; i < P2_PER_THREAD; i++) {
        int idx = base + i * 256 + tid;
        int b = -1, r = 0;
        if (idx < E) {
            b = dst[idx] >> BK_SHIFT;
            r = atomicAdd(&lcnt[b], 1);
        }
        myb[i] = b;
        myr[i] = r;
    }
    __syncthreads();
    int v = lcnt[tid];
    lbase[tid] = v;
    __syncthreads();
    for (int off = 1; off < 256; off <<= 1) {
        int t = (tid >= off) ? lbase[tid - off] : 0;
        __syncthreads();
        lbase[tid] += t;
        __syncthreads();
    }
    int excl = lbase[tid] - v;
    if (tid < nbuk && v > 0) lgpos[tid] = atomicAdd(&bucketCursor[tid], v);
    __syncthreads();
    lbase[tid] = excl;
    __syncthreads();
#pragma unroll
    for (int i = 0; i < P2_PER_THREAD; i++) {
        if (myb[i] >= 0) {
            int p = lbase[myb[i]] + myr[i];
            lsort[p] = base + i * 256 + tid;
            lbuk[p] = (unsigned char)myb[i];
        }
    }
    __syncthreads();
    int total = (base + P2_CHUNK <= E) ? P2_CHUNK : (E > base ? E - base : 0);
    for (int idx = tid; idx < total; idx += 256) {
        int b = lbuk[idx];
        inter[lgpos[b] + (idx - lbase[b])] = lsort[idx];
    }
}

// pass 3: one block per bucket. LDS per-node histogram + scan -> writes offs;
// LDS-cached edge ids/dst; sorts + fills srcS/basisB (single-writer region).
__global__ __launch_bounds__(256) void bucket_sort_fill_kernel(const int* __restrict__ inter,
                                                               const int* __restrict__ dst,
                                                               const int* __restrict__ src,
                                                               const float* __restrict__ el,
                                                               const int* __restrict__ bukbase,
                                                               int* __restrict__ offs,
                                                               int* __restrict__ srcS,
                                                               unsigned short* __restrict__ basisB,
                                                               int nN, int nbuk) {
    __shared__ int hist[256];
    __shared__ int cursor[256];
    __shared__ int eloc[BCAP];
    __shared__ unsigned char dloc[BCAP];
    int b = blockIdx.x;
    int n0 = b << BK_SHIFT;
    int n1 = min(n0 + 256, nN);
    int nn = n1 - n0;
    int tid = threadIdx.x;
    int p0 = bukbase[b], p1 = bukbase[b + 1];
    int cnt = p1 - p0;
    bool cached = (cnt <= BCAP);
    hist[tid] = 0;
    __syncthreads();
    for (int i = tid; i < cnt; i += 256) {
        int e = inter[p0 + i];
        int d = dst[e] - n0;
        if (cached) { eloc[i] = e; dloc[i] = (unsigned char)d; }
        atomicAdd(&hist[d], 1);
    }
    __syncthreads();
    int v = hist[tid];
    cursor[tid] = v;
    __syncthreads();
#pragma unroll
    for (int off = 1; off < 256; off <<= 1) {
        int t = (tid >= off) ? cursor[tid - off] : 0;
        __syncthreads();
        cursor[tid] += t;
        __syncthreads();
    }
    int ex = cursor[tid] - v;  // exclusive prefix within bucket
    if (tid < nn) offs[n0 + tid] = p0 + ex;
    if (b == nbuk - 1 && tid == 0) offs[nN] = p1;
    __syncthreads();
    cursor[tid] = p0 + ex;
    __syncthreads();
    for (int i = tid; i < cnt; i += 256) {
        int e, d;
        if (cached) { e = eloc[i]; d = dloc[i]; }
        else        { e = inter[p0 + i]; d = dst[e] - n0; }
        int pos = atomicAdd(&cursor[d], 1);
        srcS[pos] = src[e];
        float2 xy = *(const float2*)(el + 2 * (size_t)e);
        u16x8 p;
        p[0] = f2bf_bits(1.0f);
        p[1] = f2bf_bits(__sinf(PI_F * xy.x));
        p[2] = f2bf_bits(__cosf(PI_F * xy.x));
        p[3] = f2bf_bits(__sinf(2.0f * PI_F * xy.x));
        p[4] = f2bf_bits(1.0f);
        p[5] = f2bf_bits(__sinf(PI_F * xy.y));
        p[6] = f2bf_bits(__cosf(PI_F * xy.y));
        p[7] = f2bf_bits(__sinf(2.0f * PI_F * xy.y));
        *(u16x8*)(basisB + (size_t)pos * 8) = p;
    }
}

// ---------------- preps ----------------

__global__ void prep_w_kernel(const float* __restrict__ W, __hip_bfloat16* __restrict__ Wt, int K) {
    int i = blockIdx.x * 256 + threadIdx.x;
    if (i >= K * 64) return;
    int k = i >> 6, o = i & 63;
    Wt[(size_t)o * K + k] = __float2bfloat16(W[i]);
}

__global__ void prep_f2b_kernel(const float* __restrict__ in, __hip_bfloat16* __restrict__ out, int n) {
    int i = blockIdx.x * 256 + threadIdx.x;
    if (i < n) out[i] = __float2bfloat16(in[i]);
}

// ---------------- agg F=64: wave per node, lane = (eg 0..3, fg 0..15) ----------------
// r11 optimum: 256-thread blocks, depth-1 3-stage loop-carried pipeline.

__device__ __forceinline__ void agg64_core(const unsigned short* __restrict__ hp,
                                           const int* __restrict__ srcS,
                                           const unsigned short* __restrict__ basisB,
                                           int start, int end, int eg, int fb,
                                           float acc[8][4]) {
    const int last = end - 1;
    int j = start;
    int qa = min(j + eg, last), qb = min(j + 4 + eg, last);
    int sa = srcS[qa], sb = srcS[qb];
    u16x4 ga = *(const u16x4*)(hp + (size_t)sa * 64 + fb);
    u16x4 gb = *(const u16x4*)(hp + (size_t)sb * 64 + fb);
    u16x8 ca = *(const u16x8*)(basisB + (size_t)qa * 8);
    u16x8 cb = *(const u16x8*)(basisB + (size_t)qb * 8);
    int qna = min(j + 8 + eg, last), qnb = min(j + 12 + eg, last);
    int sna = srcS[qna], snb = srcS[qnb];
    while (true) {
        int jn = j + 8;
        int q2a = min(jn + 8 + eg, last), q2b = min(jn + 12 + eg, last);
        int s2a = srcS[q2a], s2b = srcS[q2b];
        u16x4 gna = *(const u16x4*)(hp + (size_t)sna * 64 + fb);
        u16x4 gnb = *(const u16x4*)(hp + (size_t)snb * 64 + fb);
        u16x8 cna = *(const u16x8*)(basisB + (size_t)qna * 8);
        u16x8 cnb = *(const u16x8*)(basisB + (size_t)qnb * 8);
        float ha[4], hb[4];
        ha[0] = bf2f(ga[0]); ha[1] = bf2f(ga[1]); ha[2] = bf2f(ga[2]); ha[3] = bf2f(ga[3]);
        hb[0] = bf2f(gb[0]); hb[1] = bf2f(gb[1]); hb[2] = bf2f(gb[2]); hb[3] = bf2f(gb[3]);
        if (j + eg >= end)     { ha[0] = 0.f; ha[1] = 0.f; ha[2] = 0.f; ha[3] = 0.f; }
        if (j + 4 + eg >= end) { hb[0] = 0.f; hb[1] = 0.f; hb[2] = 0.f; hb[3] = 0.f; }
#pragma unroll
        for (int b = 0; b < 8; b++) {
            float w = bf2f(ca[b]);
#pragma unroll
            for (int c = 0; c < 4; c++) acc[b][c] += w * ha[c];
        }
#pragma unroll
        for (int b = 0; b < 8; b++) {
            float w = bf2f(cb[b]);
#pragma unroll
            for (int c = 0; c < 4; c++) acc[b][c] += w * hb[c];
        }
        if (jn >= end) break;
        j = jn;
        ga = gna; gb = gnb; ca = cna; cb = cnb;
        qna = q2a; qnb = q2b; sna = s2a; snb = s2b;
    }
}

__global__ __launch_bounds__(256) void agg64_kernel(const __hip_bfloat16* __restrict__ h,
                                                    const int* __restrict__ srcS,
                                                    const unsigned short* __restrict__ basisB,
                                                    const int* __restrict__ offs,
                                                    __hip_bfloat16* __restrict__ A, int nN) {
    int wid = (blockIdx.x * 256 + threadIdx.x) >> 6;
    int lane = threadIdx.x & 63;
    if (wid >= nN) return;
    int eg = lane >> 4, fg = lane & 15;
    int start = offs[wid], end = offs[wid + 1];
    float acc[8][4] = {};
    if (start < end)
        agg64_core((const unsigned short*)h, srcS, basisB, start, end, eg, fg * 4, acc);
#pragma unroll
    for (int b = 0; b < 8; b++) {
#pragma unroll
        for (int c = 0; c < 4; c++) {
            float v = acc[b][c];
            v += __shfl_xor(v, 16, 64);
            v += __shfl_xor(v, 32, 64);
            acc[b][c] = v;
        }
    }
    if (eg == 0) {
        unsigned short* Ar = (unsigned short*)A + (size_t)wid * 512;
#pragma unroll
        for (int b = 0; b < 8; b++) {
            u16x4 p;
            p[0] = f2bf_bits(acc[b][0]); p[1] = f2bf_bits(acc[b][1]);
            p[2] = f2bf_bits(acc[b][2]); p[3] = f2bf_bits(acc[b][3]);
            *(u16x4*)(Ar + b * 64 + fg * 4) = p;
        }
    }
}

// fused final layer: agg64 + [512x2] contraction + scale
__global__ __launch_bounds__(256) void agg_out_kernel(const __hip_bfloat16* __restrict__ h,
                                                      const int* __restrict__ srcS,
                                                      const unsigned short* __restrict__ basisB,
                                                      const int* __restrict__ offs,
                                                      const float* __restrict__ W3,
                                                      float* __restrict__ out, int nN) {
    int wid = (blockIdx.x * 256 + threadIdx.x) >> 6;
    int lane = threadIdx.x & 63;
    if (wid >= nN) return;
    int eg = lane >> 4, fg = lane & 15;
    int start = offs[wid], end = offs[wid + 1];
    float acc[8][4] = {};
    if (start < end)
        agg64_core((const unsigned short*)h, srcS, basisB, start, end, eg, fg * 4, acc);
#pragma unroll
    for (int b = 0; b < 8; b++) {
#pragma unroll
        for (int c = 0; c < 4; c++) {
            float v = acc[b][c];
            v += __shfl_xor(v, 16, 64);
            v += __shfl_xor(v, 32, 64);
            acc[b][c] = v;
        }
    }
    float o0 = 0.f, o1 = 0.f;
#pragma unroll
    for (int b = 0; b < 8; b++) {
        const float* w = W3 + (size_t)(b * 64 + fg * 4) * 2;
        float4 wa = *(const float4*)w;
        float4 wb = *(const float4*)(w + 4);
        o0 += acc[b][0] * wa.x + acc[b][1] * wa.z + acc[b][2] * wb.x + acc[b][3] * wb.z;
        o1 += acc[b][0] * wa.y + acc[b][1] * wa.w + acc[b][2] * wb.y + acc[b][3] * wb.w;
    }
#pragma unroll
    for (int m = 1; m < 16; m <<= 1) {
        o0 += __shfl_xor(o0, m, 64);
        o1 += __shfl_xor(o1, m, 64);
    }
    if (lane == 0) {
        out[(size_t)wid * 2 + 0] = o0 * (1.0f / 128.0f);
        out[(size_t)wid * 2 + 1] = o1 * (1.0f / 128.0f);
    }
}

// ---------------- agg F=16: wave per node, lane = (eg 0..15, fg 0..3) ----------------

__global__ __launch_bounds__(256) void agg16_kernel(const __hip_bfloat16* __restrict__ h,
                                                    const int* __restrict__ srcS,
                                                    const unsigned short* __restrict__ basisB,
                                                    const int* __restrict__ offs,
                                                    __hip_bfloat16* __restrict__ A, int nN) {
    int wid = (blockIdx.x * 256 + threadIdx.x) >> 6;
    int lane = threadIdx.x & 63;
    if (wid >= nN) return;
    int eg = lane >> 2, fg = lane & 3;
    int start = offs[wid], end = offs[wid + 1];
    float acc[8][4] = {};
    if (start < end) {
        const unsigned short* hp = (const unsigned short*)h;
        const int last = end - 1;
        const int fb = fg * 4;
        int j = start;
        int q = min(j + eg, last);
        int s = srcS[q];
        u16x4 g = *(const u16x4*)(hp + (size_t)s * 16 + fb);
        u16x8 cbv = *(const u16x8*)(basisB + (size_t)q * 8);
        int qn = min(j + 16 + eg, last);
        int sn = srcS[qn];
        while (true) {
            int jn = j + 16;
            int q2 = min(jn + 16 + eg, last);
            int s2 = srcS[q2];
            u16x4 gn = *(const u16x4*)(hp + (size_t)sn * 16 + fb);
            u16x8 cn = *(const u16x8*)(basisB + (size_t)qn * 8);
            float hv[4];
            hv[0] = bf2f(g[0]); hv[1] = bf2f(g[1]); hv[2] = bf2f(g[2]); hv[3] = bf2f(g[3]);
            if (j + eg >= end) { hv[0] = 0.f; hv[1] = 0.f; hv[2] = 0.f; hv[3] = 0.f; }
#pragma unroll
            for (int b = 0; b < 8; b++) {
                float w = bf2f(cbv[b]);
#pragma unroll
                for (int c = 0; c < 4; c++) acc[b][c] += w * hv[c];
            }
            if (jn >= end) break;
            j = jn;
            g = gn; cbv = cn; qn = q2; sn = s2;
        }
    }
#pragma unroll
    for (int b = 0; b < 8; b++) {
#pragma unroll
        for (int c = 0; c < 4; c++) {
            float v = acc[b][c];
            v += __shfl_xor(v, 4, 64);
            v += __shfl_xor(v, 8, 64);
            v += __shfl_xor(v, 16, 64);
            v += __shfl_xor(v, 32, 64);
            acc[b][c] = v;
        }
    }
    if (eg == 0) {
        unsigned short* Ar = (unsigned short*)A + (size_t)wid * 128;
#pragma unroll
        for (int b = 0; b < 8; b++) {
            u16x4 p;
            p[0] = f2bf_bits(acc[b][0]); p[1] = f2bf_bits(acc[b][1]);
            p[2] = f2bf_bits(acc[b][2]); p[3] = f2bf_bits(acc[b][3]);
            *(u16x4*)(Ar + b * 16 + fg * 4) = p;
        }
    }
}

// ---------------- MFMA GEMM: Hout[n, 0..63] = relu(A[n, :K] @ Wt^T), bf16 out ----------------
// Frags (16x16x32 bf16): A/B lane mapping m/n = lane&15, k = (lane>>4)*8 + j.
// C/D: col = lane&15, row = (lane>>4)*4 + reg  [verified m89].

template <int K, bool RELU>
__global__ __launch_bounds__(256) void gemm_mfma_kernel(const __hip_bfloat16* __restrict__ A,
                                                        const __hip_bfloat16* __restrict__ Wt,
                                                        __hip_bfloat16* __restrict__ Hout, int nN) {
    int wave = threadIdx.x >> 6;
    int lane = threadIdx.x & 63;
    int m16 = lane & 15;
    int kg = lane >> 4;  // 0..3
    int arow = blockIdx.x * 64 + wave * 16 + m16;
    bool rowok = arow < nN;
    const short* Ap = (const short*)A;
    const short* Wp = (const short*)Wt;
    size_t abase = (size_t)arow * K + kg * 8;
    size_t wb0 = (size_t)(0 * 16 + m16) * K + kg * 8;
    size_t wb1 = (size_t)(1 * 16 + m16) * K + kg * 8;
    size_t wb2 = (size_t)(2 * 16 + m16) * K + kg * 8;
    size_t wb3 = (size_t)(3 * 16 + m16) * K + kg * 8;
    f32x4 acc0 = {0.f, 0.f, 0.f, 0.f};
    f32x4 acc1 = {0.f, 0.f, 0.f, 0.f};
    f32x4 acc2 = {0.f, 0.f, 0.f, 0.f};
    f32x4 acc3 = {0.f, 0.f, 0.f, 0.f};
#pragma unroll 4
    for (int kc = 0; kc < K; kc += 32) {
        bf16x8 af = {};
        if (rowok) af = *(const bf16x8*)(Ap + abase + kc);
        bf16x8 b0 = *(const bf16x8*)(Wp + wb0 + kc);
        bf16x8 b1 = *(const bf16x8*)(Wp + wb1 + kc);
        bf16x8 b2 = *(const bf16x8*)(Wp + wb2 + kc);
        bf16x8 b3 = *(const bf16x8*)(Wp + wb3 + kc);
        acc0 = __builtin_amdgcn_mfma_f32_16x16x32_bf16(af, b0, acc0, 0, 0, 0);
        acc1 = __builtin_amdgcn_mfma_f32_16x16x32_bf16(af, b1, acc1, 0, 0, 0);
        acc2 = __builtin_amdgcn_mfma_f32_16x16x32_bf16(af, b2, acc2, 0, 0, 0);
        acc3 = __builtin_amdgcn_mfma_f32_16x16x32_bf16(af, b3, acc3, 0, 0, 0);
    }
    int orow0 = blockIdx.x * 64 + wave * 16 + kg * 4;
#pragma unroll
    for (int r = 0; r < 4; r++) {
        int row = orow0 + r;
        if (row < nN) {
            float v0 = acc0[r], v1 = acc1[r], v2 = acc2[r], v3 = acc3[r];
            if (RELU) {
                v0 = fmaxf(v0, 0.0f); v1 = fmaxf(v1, 0.0f);
                v2 = fmaxf(v2, 0.0f); v3 = fmaxf(v3, 0.0f);
            }
            __hip_bfloat16* Hr = Hout + (size_t)row * 64;
            Hr[0 * 16 + m16] = __float2bfloat16(v0);
            Hr[1 * 16 + m16] = __float2bfloat16(v1);
            Hr[2 * 16 + m16] = __float2bfloat16(v2);
            Hr[3 * 16 + m16] = __float2bfloat16(v3);
        }
    }
}

// ---------------- launch ----------------

extern "C" void kernel_launch(void* const* d_in, const int* in_sizes, int n_in,
                              void* d_out, int out_size, void* d_ws, size_t ws_size,
                              hipStream_t stream) {
    const float* x  = (const float*)d_in[0];
    const int*   ei = (const int*)d_in[1];
    const float* el = (const float*)d_in[2];
    const float* W0 = (const float*)d_in[3];
    const float* W1 = (const float*)d_in[4];
    const float* W2 = (const float*)d_in[5];
    const float* W3 = (const float*)d_in[6];
    int nN = in_sizes[0] / 16;
    int E  = in_sizes[1] / 2;
    const int* src = ei;
    const int* dst = ei + E;

    char* ws = (char*)d_ws;
    size_t off = 0;
    auto alloc = [&](size_t bytes) -> void* {
        void* p = ws + off;
        off = (off + bytes + 255) & ~(size_t)255;
        return p;
    };
    int nbuk = (nN + 255) >> BK_SHIFT;  // buckets of 256 nodes (196)
    int*   bcnt    = (int*)alloc((size_t)nbuk * 4);
    int*   bukbase = (int*)alloc((size_t)(nbuk + 1) * 4);
    int*   bukcur  = (int*)alloc((size_t)nbuk * 4);
    int*   offs    = (int*)alloc((size_t)(nN + 1) * 4);
    int*   inter   = (int*)alloc((size_t)E * 4);
    int*   srcS    = (int*)alloc((size_t)E * 4);
    unsigned short* basisB = (unsigned short*)alloc((size_t)E * 8 * 2);
    __hip_bfloat16* Ab  = (__hip_bfloat16*)alloc((size_t)nN * 512 * 2);
    __hip_bfloat16* Wt0 = (__hip_bfloat16*)alloc((size_t)64 * 128 * 2);
    __hip_bfloat16* Wt1 = (__hip_bfloat16*)alloc((size_t)64 * 512 * 2);
    __hip_bfloat16* Wt2 = (__hip_bfloat16*)alloc((size_t)64 * 512 * 2);
    __hip_bfloat16* xb  = (__hip_bfloat16*)alloc((size_t)nN * 16 * 2);
    __hip_bfloat16* hA  = (__hip_bfloat16*)alloc((size_t)nN * 64 * 2);
    __hip_bfloat16* hB  = (__hip_bfloat16*)alloc((size_t)nN * 64 * 2);
    (void)ws_size;

    hipMemsetAsync(bcnt, 0, (size_t)nbuk * 4, stream);
    int p2b = (E + P2_CHUNK - 1) / P2_CHUNK;
    bucket_count_kernel<<<p2b, 256, 0, stream>>>(dst, bcnt, E, nbuk);
    bucket_scan_kernel<<<1, 256, 0, stream>>>(bcnt, bukbase, bukcur, nbuk, E);
    bucket_scatter_kernel<<<p2b, 256, 0, stream>>>(dst, bukcur, inter, E, nbuk);
    bucket_sort_fill_kernel<<<nbuk, 256, 0, stream>>>(inter, dst, src, el, bukbase, offs,
                                                      srcS, basisB, nN, nbuk);

    // preps (independent of binning; tiny)
    prep_w_kernel<<<(128 * 64 + 255) / 256, 256, 0, stream>>>(W0, Wt0, 128);
    prep_w_kernel<<<(512 * 64 + 255) / 256, 256, 0, stream>>>(W1, Wt1, 512);
    prep_w_kernel<<<(512 * 64 + 255) / 256, 256, 0, stream>>>(W2, Wt2, 512);
    prep_f2b_kernel<<<(nN * 16 + 255) / 256, 256, 0, stream>>>(x, xb, nN * 16);

    int nb = (nN + 3) / 4;    // 1 wave per node
    int gb = (nN + 63) / 64;  // gemm tiles

    // layer 0: in=16 -> 64
    agg16_kernel<<<nb, 256, 0, stream>>>(xb, srcS, basisB, offs, Ab, nN);
    gemm_mfma_kernel<128, true><<<gb, 256, 0, stream>>>(Ab, Wt0, hA, nN);
    // layer 1: 64 -> 64
    agg64_kernel<<<nb, 256, 0, stream>>>(hA, srcS, basisB, offs, Ab, nN);
    gemm_mfma_kernel<512, true><<<gb, 256, 0, stream>>>(Ab, Wt1, hB, nN);
    // layer 2: 64 -> 64
    agg64_kernel<<<nb, 256, 0, stream>>>(hB, srcS, basisB, offs, Ab, nN);
    gemm_mfma_kernel<512, true><<<gb, 256, 0, stream>>>(Ab, Wt2, hA, nN);
    // layer 3 fused: agg + [512x2] + scale
    agg_out_kernel<<<nb, 256, 0, stream>>>(hA, srcS, basisB, offs, W3, (float*)d_out, nN);
}